// Round 15
// baseline (666.544 us; speedup 1.0000x reference)
//
#include <hip/hip_runtime.h>
#include <hip/hip_fp16.h>

#define D 128
#define TILE 16384
#define NOCT 8
typedef unsigned long long ull;
typedef _Float16 half8 __attribute__((ext_vector_type(8)));
typedef _Float16 half4v __attribute__((ext_vector_type(4)));
typedef float f32x4 __attribute__((ext_vector_type(4)));

// k-permutation: quartet k4 -> LDS pos so each MFMA fragment is one ds_read_b128
#define KPOS(k4) (((k4) & ~31) + ((((k4) & 15) >> 2) << 3) + ((((k4) >> 4) & 1) << 2))

// ---- 1a: per-tile bucket histogram (bucket = dst>>9), LDS only ----
__global__ void k_cnt_tiles(const int* __restrict__ ei_dst, int* __restrict__ cnt,
                            int E, int ntiles, int nb) {
  __shared__ int h[256];
  for (int i = threadIdx.x; i < nb; i += 256) h[i] = 0;
  __syncthreads();
  const int t = blockIdx.x;
  const int start = t * TILE;
  int end = start + TILE;
  if (end > E) end = E;
  for (int i = start + threadIdx.x; i < end; i += 256)
    atomicAdd(&h[__builtin_nontemporal_load(&ei_dst[i]) >> 9], 1);
  __syncthreads();
  for (int b = threadIdx.x; b < nb; b += 256)
    cnt[(size_t)b * ntiles + t] = h[b];
}

// ---- 1b: off[b][t] = base(b) + prefix over tiles; single block, no atomics ----
__global__ void k_tile_scan(const int* __restrict__ cnt, int* __restrict__ off,
                            int nb, int ntiles) {
  __shared__ int sd[256];
  int total = 0;
  if (threadIdx.x < nb) {
    const int* row = cnt + (size_t)threadIdx.x * ntiles;
    for (int t = 0; t < ntiles; t++) total += row[t];
  }
  sd[threadIdx.x] = total;
  __syncthreads();
  for (int o = 1; o < 256; o <<= 1) {
    int v = (threadIdx.x >= o) ? sd[threadIdx.x - o] : 0;
    __syncthreads();
    sd[threadIdx.x] += v;
    __syncthreads();
  }
  int base = sd[threadIdx.x] - total;  // exclusive
  if (threadIdx.x < nb) {
    const int* row = cnt + (size_t)threadIdx.x * ntiles;
    int* orow = off + (size_t)threadIdx.x * ntiles;
    int run = base;
    for (int t = 0; t < ntiles; t++) { orow[t] = run; run += row[t]; }
  }
}

// ---- 1c: scatter edges into bucket-major runs (LDS rank, no global atomics) ----
__global__ void k_scatter_bucket(const int* __restrict__ ei, const int* __restrict__ off,
                                 ull* __restrict__ ebb, int E, int ntiles, int nb) {
  __shared__ int h[256];
  __shared__ int base[256];
  const int t = blockIdx.x;
  for (int i = threadIdx.x; i < nb; i += 256) {
    h[i] = 0;
    base[i] = off[(size_t)i * ntiles + t];
  }
  __syncthreads();
  const int start = t * TILE;
  int end = start + TILE;
  if (end > E) end = E;
  for (int i = start + threadIdx.x; i < end; i += 256) {
    int d = __builtin_nontemporal_load(&ei[E + i]);
    int s = __builtin_nontemporal_load(&ei[i]);
    int b = d >> 9;
    int r = atomicAdd(&h[b], 1);
    ebb[(size_t)base[b] + r] = (ull)(unsigned)s | ((ull)(unsigned)d << 32);
  }
}

// ---- 2: fused per-bucket {(node,octant) count, LDS scan -> rowptr/dinv/cursors, fill} ----
// csr per node is stored grouped by src-octant (oct = src/octw) so the aggregate's
// linear sweep visits th slices 0..7 in order -> cross-block L2 phase locality.
__global__ void k_fill_bucket2(const ull* __restrict__ ebb, const int* __restrict__ off,
                               int* __restrict__ rowptr, float* __restrict__ dinv,
                               int* __restrict__ csr, int E, int ntiles, int nb, int N,
                               unsigned octw) {
  __shared__ int cnt[512 * NOCT];   // (node,oct) counts, then cursors (16 KB)
  __shared__ int ps[256];
  const int b = blockIdx.x;
  const int tid = threadIdx.x;
  const int lo = off[(size_t)b * ntiles];
  const int hi = (b + 1 < nb) ? off[(size_t)(b + 1) * ntiles] : E;
  for (int i = tid; i < 512 * NOCT; i += 256) cnt[i] = 0;
  __syncthreads();
  // pass 1: histogram by (local node, src octant)
  for (int i = lo + tid; i < hi; i += 256) {
    ull q = __builtin_nontemporal_load(&ebb[i]);
    int s = (int)(unsigned)q;
    int dl = (int)(q >> 32) - (b << 9);
    int oct = (int)((unsigned)s / octw);
    atomicAdd(&cnt[dl * NOCT + oct], 1);
  }
  __syncthreads();
  // LDS scan over 4096 entries (16 per thread; thread covers local nodes 2t,2t+1)
  int loc[16];
  int ssum = 0;
#pragma unroll
  for (int k = 0; k < 16; k++) {
    loc[k] = cnt[tid * 16 + k];
    ssum += loc[k];
  }
  ps[tid] = ssum;
  __syncthreads();
  for (int o = 1; o < 256; o <<= 1) {
    int v = (tid >= o) ? ps[tid - o] : 0;
    __syncthreads();
    ps[tid] += v;
    __syncthreads();
  }
  int run = lo + ps[tid] - ssum;     // exclusive offset of entry tid*16
  int v0 = (b << 9) + 2 * tid;
  int v1 = v0 + 1;
  int deg0 = 0, deg1 = 0;
#pragma unroll
  for (int k = 0; k < 8; k++) deg0 += loc[k];
#pragma unroll
  for (int k = 8; k < 16; k++) deg1 += loc[k];
  if (v0 < N) {
    rowptr[v0] = run;
    dinv[v0] = rsqrtf((float)deg0 + 1.0f);
  }
  if (v1 < N) {
    rowptr[v1] = run + deg0;
    dinv[v1] = rsqrtf((float)deg1 + 1.0f);
  }
  if (b == 0 && tid == 0) rowptr[N] = E;
  {
    int r = run;
#pragma unroll
    for (int k = 0; k < 16; k++) {
      cnt[tid * 16 + k] = r;   // cursor start for this (node,oct)
      r += loc[k];
    }
  }
  __syncthreads();
  // pass 2: fill (ebb chunk ~130KB is L2-resident from pass 1)
  for (int i = lo + tid; i < hi; i += 256) {
    ull q = __builtin_nontemporal_load(&ebb[i]);
    int s = (int)(unsigned)q;
    int dl = (int)(q >> 32) - (b << 9);
    int oct = (int)((unsigned)s / octw);
    int pos = atomicAdd(&cnt[dl * NOCT + oct], 1);
    csr[pos] = s;
  }
}

// ---------------- MFMA GEMM: Th[n,128](fp16) = (A[n,128] @ W[128,128]) * dinv[row] ----
template <int HALF_IN>
__launch_bounds__(256, 2)
__global__ void k_gemm_mfma(const void* __restrict__ Av, const float* __restrict__ W,
                            const float* __restrict__ dinv, __half* __restrict__ Th, int n) {
  __shared__ _Float16 Al[128 * 136];
  __shared__ _Float16 Bl[128 * 136];
  const int tid = threadIdx.x;
  const int row0 = blockIdx.x * 128;

  if (HALF_IN) {
    const _Float16* A = (const _Float16*)Av;
    for (int i = tid; i < 2048; i += 256) {
      int r = i >> 4;
      int k8 = (i & 15) << 3;
      half8 v = {0, 0, 0, 0, 0, 0, 0, 0};
      if (row0 + r < n) v = *(const half8*)&A[(size_t)(row0 + r) * D + k8];
      *(half4v*)&Al[r * 136 + KPOS(k8)]     = (half4v){v[0], v[1], v[2], v[3]};
      *(half4v*)&Al[r * 136 + KPOS(k8 + 4)] = (half4v){v[4], v[5], v[6], v[7]};
    }
  } else {
    const float* A = (const float*)Av;
    for (int i = tid; i < 4096; i += 256) {
      int r = i >> 5;
      int k4 = (i & 31) << 2;
      float4 v = make_float4(0.f, 0.f, 0.f, 0.f);
      if (row0 + r < n) v = ((const float4*)A)[(size_t)(row0 + r) * 32 + (i & 31)];
      *(half4v*)&Al[r * 136 + KPOS(k4)] =
          (half4v){(_Float16)v.x, (_Float16)v.y, (_Float16)v.z, (_Float16)v.w};
    }
  }
  for (int i = tid; i < 4096; i += 256) {
    int c = i & 127;
    int k4 = (i >> 7) << 2;
    float w0 = W[(k4 + 0) * D + c];
    float w1 = W[(k4 + 1) * D + c];
    float w2 = W[(k4 + 2) * D + c];
    float w3 = W[(k4 + 3) * D + c];
    *(half4v*)&Bl[c * 136 + KPOS(k4)] =
        (half4v){(_Float16)w0, (_Float16)w1, (_Float16)w2, (_Float16)w3};
  }
  __syncthreads();

  const int w = tid >> 6;
  const int lane = tid & 63;
  const int g = lane >> 4;
  const int q = lane & 15;

  f32x4 acc[2][8];
#pragma unroll
  for (int mt = 0; mt < 2; mt++)
#pragma unroll
    for (int nt = 0; nt < 8; nt++) acc[mt][nt] = (f32x4){0.f, 0.f, 0.f, 0.f};

#pragma unroll
  for (int kt = 0; kt < 4; kt++) {
    half8 a[2], bb[8];
#pragma unroll
    for (int mt = 0; mt < 2; mt++)
      a[mt] = *(const half8*)&Al[(w * 32 + mt * 16 + q) * 136 + kt * 32 + g * 8];
#pragma unroll
    for (int nt = 0; nt < 8; nt++)
      bb[nt] = *(const half8*)&Bl[(nt * 16 + q) * 136 + kt * 32 + g * 8];
#pragma unroll
    for (int mt = 0; mt < 2; mt++)
#pragma unroll
      for (int nt = 0; nt < 8; nt++)
        acc[mt][nt] = __builtin_amdgcn_mfma_f32_16x16x32_f16(a[mt], bb[nt], acc[mt][nt], 0, 0, 0);
  }

#pragma unroll
  for (int mt = 0; mt < 2; mt++) {
    int baseRow = row0 + w * 32 + mt * 16 + g * 4;
    float dv[4];
#pragma unroll
    for (int r = 0; r < 4; r++) dv[r] = (baseRow + r < n) ? dinv[baseRow + r] : 0.f;
#pragma unroll
    for (int nt = 0; nt < 8; nt++) {
      int col = nt * 16 + q;
#pragma unroll
      for (int r = 0; r < 4; r++) {
        int gr = baseRow + r;
        if (gr < n) Th[(size_t)gr * D + col] = (__half)(acc[mt][nt][r] * dv[r]);
      }
    }
  }
}

// ---------------- pull-style aggregation (fp16 gathers, unroll 8, grid-stride) ----------------
// grid-stride with exactly-resident grid keeps all blocks alive & in octant-phase.
template <int MODE>
__launch_bounds__(256)
__global__ void k_aggregate(const int* __restrict__ rowptr, const int* __restrict__ csr,
                            const float* __restrict__ dinv, const __half* __restrict__ th,
                            const float* __restrict__ b, const __half* __restrict__ resh,
                            __half* __restrict__ outh, float* __restrict__ outf, int n) {
  const int g = threadIdx.x >> 4;
  const int l16 = threadIdx.x & 15;
  const float4* t4 = (const float4*)th;
  const float4* b4 = (const float4*)b;
  float4 bb0 = b4[l16 * 2];
  float4 bb1 = b4[l16 * 2 + 1];

  for (int node = blockIdx.x * 16 + g; node < n; node += gridDim.x * 16) {
    int beg = rowptr[node];
    int end = rowptr[node + 1];
    float dd = dinv[node];

    float a0, a1, a2, a3, a4, a5, a6, a7;
    {
      float4 raw = t4[(size_t)node * 16 + l16];   // self term
      const __half2* hp = (const __half2*)&raw;
      float2 f0 = __half22float2(hp[0]);
      float2 f1 = __half22float2(hp[1]);
      float2 f2 = __half22float2(hp[2]);
      float2 f3 = __half22float2(hp[3]);
      a0 = f0.x; a1 = f0.y; a2 = f1.x; a3 = f1.y;
      a4 = f2.x; a5 = f2.y; a6 = f3.x; a7 = f3.y;
    }

#define ACC_ROW(raw)                                  \
  {                                                   \
    const __half2* hp = (const __half2*)&(raw);       \
    float2 f0 = __half22float2(hp[0]);                \
    float2 f1 = __half22float2(hp[1]);                \
    float2 f2 = __half22float2(hp[2]);                \
    float2 f3 = __half22float2(hp[3]);                \
    a0 += f0.x; a1 += f0.y; a2 += f1.x; a3 += f1.y;   \
    a4 += f2.x; a5 += f2.y; a6 += f3.x; a7 += f3.y;   \
  }

    int j = beg;
    for (; j + 8 <= end; j += 8) {
      float4 r0, r1, r2, r3, r4, r5, r6, r7;
      {
        int s0 = __builtin_nontemporal_load(&csr[j + 0]);
        int s1 = __builtin_nontemporal_load(&csr[j + 1]);
        int s2 = __builtin_nontemporal_load(&csr[j + 2]);
        int s3 = __builtin_nontemporal_load(&csr[j + 3]);
        int s4 = __builtin_nontemporal_load(&csr[j + 4]);
        int s5 = __builtin_nontemporal_load(&csr[j + 5]);
        int s6 = __builtin_nontemporal_load(&csr[j + 6]);
        int s7 = __builtin_nontemporal_load(&csr[j + 7]);
        r0 = t4[(size_t)(unsigned)s0 * 16 + l16];
        r1 = t4[(size_t)(unsigned)s1 * 16 + l16];
        r2 = t4[(size_t)(unsigned)s2 * 16 + l16];
        r3 = t4[(size_t)(unsigned)s3 * 16 + l16];
        r4 = t4[(size_t)(unsigned)s4 * 16 + l16];
        r5 = t4[(size_t)(unsigned)s5 * 16 + l16];
        r6 = t4[(size_t)(unsigned)s6 * 16 + l16];
        r7 = t4[(size_t)(unsigned)s7 * 16 + l16];
      }
      ACC_ROW(r0) ACC_ROW(r1) ACC_ROW(r2) ACC_ROW(r3)
      ACC_ROW(r4) ACC_ROW(r5) ACC_ROW(r6) ACC_ROW(r7)
    }
    for (; j + 4 <= end; j += 4) {
      int s0 = __builtin_nontemporal_load(&csr[j + 0]);
      int s1 = __builtin_nontemporal_load(&csr[j + 1]);
      int s2 = __builtin_nontemporal_load(&csr[j + 2]);
      int s3 = __builtin_nontemporal_load(&csr[j + 3]);
      float4 r0 = t4[(size_t)(unsigned)s0 * 16 + l16];
      float4 r1 = t4[(size_t)(unsigned)s1 * 16 + l16];
      float4 r2 = t4[(size_t)(unsigned)s2 * 16 + l16];
      float4 r3 = t4[(size_t)(unsigned)s3 * 16 + l16];
      ACC_ROW(r0) ACC_ROW(r1) ACC_ROW(r2) ACC_ROW(r3)
    }
    for (; j < end; ++j) {
      int s = __builtin_nontemporal_load(&csr[j]);
      float4 r = t4[(size_t)(unsigned)s * 16 + l16];
      ACC_ROW(r)
    }
#undef ACC_ROW

    float o0 = fmaf(a0, dd, bb0.x), o1 = fmaf(a1, dd, bb0.y);
    float o2 = fmaf(a2, dd, bb0.z), o3 = fmaf(a3, dd, bb0.w);
    float o4 = fmaf(a4, dd, bb1.x), o5 = fmaf(a5, dd, bb1.y);
    float o6 = fmaf(a6, dd, bb1.z), o7 = fmaf(a7, dd, bb1.w);

    if (MODE == 1) {
      float4 raw = ((const float4*)resh)[(size_t)node * 16 + l16];
      const __half2* hp = (const __half2*)&raw;
      float2 f0 = __half22float2(hp[0]);
      float2 f1 = __half22float2(hp[1]);
      float2 f2 = __half22float2(hp[2]);
      float2 f3 = __half22float2(hp[3]);
      o0 += f0.x; o1 += f0.y; o2 += f1.x; o3 += f1.y;
      o4 += f2.x; o5 += f2.y; o6 += f3.x; o7 += f3.y;
    }
    if (MODE == 0 || MODE == 1) {
      o0 = fmaxf(o0, 0.f); o1 = fmaxf(o1, 0.f); o2 = fmaxf(o2, 0.f); o3 = fmaxf(o3, 0.f);
      o4 = fmaxf(o4, 0.f); o5 = fmaxf(o5, 0.f); o6 = fmaxf(o6, 0.f); o7 = fmaxf(o7, 0.f);
      union { __half2 h[4]; float4 f; } pk;
      pk.h[0] = __floats2half2_rn(o0, o1);
      pk.h[1] = __floats2half2_rn(o2, o3);
      pk.h[2] = __floats2half2_rn(o4, o5);
      pk.h[3] = __floats2half2_rn(o6, o7);
      ((float4*)outh)[(size_t)node * 16 + l16] = pk.f;
    } else {
      ((float4*)outf)[(size_t)node * 32 + l16 * 2] = make_float4(o0, o1, o2, o3);
      ((float4*)outf)[(size_t)node * 32 + l16 * 2 + 1] = make_float4(o4, o5, o6, o7);
    }
  }
}

extern "C" void kernel_launch(void* const* d_in, const int* in_sizes, int n_in,
                              void* d_out, int out_size, void* d_ws, size_t ws_size,
                              hipStream_t stream) {
  const float* x  = (const float*)d_in[0];
  const int*   ei = (const int*)d_in[1];
  const float* W0 = (const float*)d_in[2];
  const float* b0 = (const float*)d_in[3];
  const float* W1 = (const float*)d_in[4];
  const float* b1 = (const float*)d_in[5];
  const float* W2 = (const float*)d_in[6];
  const float* b2 = (const float*)d_in[7];
  float* out = (float*)d_out;

  const int N = in_sizes[0] / D;   // 100000
  const int E = in_sizes[1] / 2;   // 3200000

  const int ntiles = (E + TILE - 1) / TILE;   // 196
  const int nb = (N + 511) >> 9;              // 196 buckets of 512 nodes
  const unsigned octw = (unsigned)((N + NOCT - 1) / NOCT);   // 12500

  char* wsb = (char*)d_ws;
  auto alloc = [&](size_t bytes) {
    char* p = wsb;
    wsb += ((bytes + 255) & ~(size_t)255);
    return p;
  };
  int*    rowptr = (int*)alloc((N + 1) * 4);
  float*  dinv   = (float*)alloc(N * 4);
  int*    cnt    = (int*)alloc((size_t)nb * ntiles * 4);
  int*    off    = (int*)alloc((size_t)nb * ntiles * 4);
  ull*    ebb    = (ull*)alloc((size_t)E * 8);
  int*    csr    = (int*)alloc((size_t)E * 4);
  __half* th     = (__half*)alloc((size_t)N * D * 2);
  __half* g1h    = (__half*)alloc((size_t)N * D * 2);
  __half* g2h    = (__half*)alloc((size_t)N * D * 2);

  dim3 b256(256);
  int gGem = (N + 127) / 128;
  int gAgg = 2048;   // exactly-resident grid: keeps blocks octant-phase-aligned

  // ---- CSR build: atomic-free counting sort, octant-ordered adjacency ----
  k_cnt_tiles<<<ntiles, b256, 0, stream>>>(ei + E, cnt, E, ntiles, nb);
  k_tile_scan<<<1, b256, 0, stream>>>(cnt, off, nb, ntiles);
  k_scatter_bucket<<<ntiles, b256, 0, stream>>>(ei, off, ebb, E, ntiles, nb);
  k_fill_bucket2<<<nb, b256, 0, stream>>>(ebb, off, rowptr, dinv, csr, E, ntiles, nb, N, octw);

  // ---- layer 0: g1 = relu(Agg(x@W0) + b0)  [fp16] ----
  k_gemm_mfma<0><<<gGem, b256, 0, stream>>>(x, W0, dinv, th, N);
  k_aggregate<0><<<gAgg, b256, 0, stream>>>(rowptr, csr, dinv, th, b0, nullptr, g1h, nullptr, N);

  // ---- layer 1: h2 = relu(Agg(g1@W1) + b1 + g1)  [fp16] ----
  k_gemm_mfma<1><<<gGem, b256, 0, stream>>>(g1h, W1, dinv, th, N);
  k_aggregate<1><<<gAgg, b256, 0, stream>>>(rowptr, csr, dinv, th, b1, g1h, g2h, nullptr, N);

  // ---- layer 2: out = Agg(h2@W2) + b2  [f32 -> d_out] ----
  k_gemm_mfma<1><<<gGem, b256, 0, stream>>>(g2h, W2, dinv, th, N);
  k_aggregate<2><<<gAgg, b256, 0, stream>>>(rowptr, csr, dinv, th, b2, nullptr, nullptr, out, N);
}